// Round 4
// baseline (177.600 us; speedup 1.0000x reference)
//
#include <hip/hip_runtime.h>
#include <math.h>

// SparseMultiheadAttention B=2,H=16,S=2048,DH=64, STRIDE=128, EXPR=32, bidirectional.
// Mask factorization (HW-validated round 0/1):
//   allowed(i,c) = (c&127)>=96 | ((c&127)==0 && c>0) | ((c>>7)==a(i))
//   a(i) = (i>>7) - ((i&127)==0 && i>0)
// Block = 512 thr = 2 wave-groups x 4 waves over the SAME 128 rows (K-split).
// Group g computes segs {g, g+2, ...}; per interval one group computes while
// the other stages its next seg (single-buffered per group); merge m/l/O at end.
// 64-col segments:
//   s0..7 : summary band pairs [256s+96,+128) u [256s+224,+256)   (no mask)
//   s8    : local A [128A,+64)                      (mask a_row==A)
//   s9    : local A [128A+64,+96)                   (nn=2, mask a_row==A)
//   s10   : 15 checkpoint cols {128k} (mask k!=a_row) + 49 special cols
//           [128(A-1),+49) (mask a_row==A-1; R>0)   (R=0: nn=2, checkpoint only)
//   s11   : special [128(A-1)+49,+96) (mask a_row==A-1 && p<47; R>0 only)
// Coverage check (per row a in {R,R-1}): summary once; local/special block once
// (checkpoint instance of col 128a masked, counted in local); checkpoints k!=a once.

namespace {

constexpr int kS = 2048, kD = 64;

typedef __attribute__((ext_vector_type(8))) short short8;
typedef __attribute__((ext_vector_type(4))) float f32x4;
typedef __attribute__((ext_vector_type(4))) unsigned int u32x4;

__device__ __forceinline__ unsigned f2bf(float f) {
    unsigned u = __builtin_bit_cast(unsigned, f);
    u += 0x7fffu + ((u >> 16) & 1u);   // RNE; inputs finite
    return u >> 16;
}
__device__ __forceinline__ unsigned pk2(float a, float b) {
    return f2bf(a) | (f2bf(b) << 16);
}
__device__ __forceinline__ unsigned short bf1(float a) {
    return (unsigned short)f2bf(a);
}

__device__ __forceinline__ int colOf(int s, int p, int A, int R) {
    if (s < 8)  return 256 * s + (p < 32 ? 96 + p : 192 + p);
    if (s == 8) return 128 * A + p;
    if (s == 9) return 128 * A + 64 + p;
    if (s == 10) {
        if (p < 15) return 128 * (p + 1);
        return (R > 0) ? (128 * (A - 1) + (p - 15)) : 0;
    }
    return 128 * (A - 1) + 49 + p;          // s==11 (R>0 only)
}
__device__ __forceinline__ bool maskOf(int s, int p, int a_row, int A, int R) {
    if (s < 8)  return true;
    if (s == 8 || s == 9) return a_row == A;
    if (s == 10) {
        if (p < 15) return a_row != (p + 1);
        return (R > 0) && (a_row == A - 1);
    }
    return (p < 47) && (a_row == A - 1);
}

__global__ __launch_bounds__(512, 4) void sparse_attn2(
    const float* __restrict__ Q, const float* __restrict__ K,
    const float* __restrict__ V, float* __restrict__ Out)
{
    // [0,32K): stage: group g at g*16K  (K 8K row-major swz ^(c&7)<<4; V^T 8K swz ^(d&7)<<4)
    // [32K,64K): ps per wave 4K  ([32][64] bf16, swz ^(row&7)<<4)
    // [64K..64K+1K): merge m/l   ; group1 O partials reuse [0,32K)
    __shared__ __align__(16) unsigned char lds[66560];

    const int tid = threadIdx.x;
    const int wv = tid >> 6, group = tid >> 8, wg = wv & 3;
    const int l = tid & 63, g = l >> 4, lm = l & 15;
    const int tid_g = tid & 255;
    const int bh = blockIdx.x >> 4, R = blockIdx.x & 15, A = R;
    const int rowbase = R * 128 + wg * 32;
    const int nseg = (R > 0) ? 12 : 11;

    const float* Qb = Q + (size_t)bh * kS * kD;
    const float* Kb = K + (size_t)bh * kS * kD;
    const float* Vb = V + (size_t)bh * kS * kD;

    // Q A-fragments (row = lm+16m, k = g*8+j+32kk), pre-scaled by 1/8
    short8 qa[2][2];
#pragma unroll
    for (int m = 0; m < 2; ++m)
#pragma unroll
    for (int kk = 0; kk < 2; ++kk) {
        const float* qp = Qb + (size_t)(rowbase + lm + 16*m) * kD + kk*32 + g*8;
        float4 a = *(const float4*)qp;
        float4 b = *(const float4*)(qp + 4);
        u32x4 t;
        t.x = pk2(a.x*0.125f, a.y*0.125f);
        t.y = pk2(a.z*0.125f, a.w*0.125f);
        t.z = pk2(b.x*0.125f, b.y*0.125f);
        t.w = pk2(b.z*0.125f, b.w*0.125f);
        qa[m][kk] = __builtin_bit_cast(short8, t);
    }

    int arow[2][4];
#pragma unroll
    for (int m = 0; m < 2; ++m)
#pragma unroll
    for (int i = 0; i < 4; ++i) {
        const int ig = rowbase + g*4 + i + 16*m;
        arow[m][i] = (ig >> 7) - (((ig & 127) == 0 && ig > 0) ? 1 : 0);
    }

    float mrun[2][4], lpar[2][4];
    f32x4 o[2][4];
#pragma unroll
    for (int m = 0; m < 2; ++m) {
#pragma unroll
        for (int i = 0; i < 4; ++i) { mrun[m][i] = -1e30f; lpar[m][i] = 0.f; }
#pragma unroll
        for (int nv = 0; nv < 4; ++nv) o[m][nv] = (f32x4){0.f,0.f,0.f,0.f};
    }

    unsigned char* ksb = lds + group * 16384;
    unsigned char* vsb = ksb + 8192;

    auto stage = [&](int s) {
        {   // K: thread = (c = tid_g>>2, quarter q4 = tid_g&3) -> 16 d-floats
            const int c  = tid_g >> 2;
            const int q4 = tid_g & 3;
            const int col = colOf(s, c, A, R);
            const float* kp = Kb + (size_t)col * kD + q4*16;
            float4 k0 = *(const float4*)(kp);
            float4 k1 = *(const float4*)(kp + 4);
            float4 k2 = *(const float4*)(kp + 8);
            float4 k3 = *(const float4*)(kp + 12);
            u32x4 lo, hi;
            lo.x = pk2(k0.x,k0.y); lo.y = pk2(k0.z,k0.w);
            lo.z = pk2(k1.x,k1.y); lo.w = pk2(k1.z,k1.w);
            hi.x = pk2(k2.x,k2.y); hi.y = pk2(k2.z,k2.w);
            hi.z = pk2(k3.x,k3.y); hi.w = pk2(k3.z,k3.w);
            const unsigned b  = (unsigned)(c*128 + q4*32);
            const unsigned sw = ((unsigned)(c & 7)) << 4;
            *(u32x4*)(ksb + (b ^ sw))        = lo;
            *(u32x4*)(ksb + ((b + 16) ^ sw)) = hi;
        }
        {   // V^T: thread = (coct = tid_g>>5 -> c0=8*coct, dp = tid_g&31 -> d0=2*dp)
            const int c0 = (tid_g >> 5) * 8;
            const int d0 = (tid_g & 31) * 2;
            float2 r[8];
#pragma unroll
            for (int j = 0; j < 8; ++j) {
                const int col = colOf(s, c0 + j, A, R);
                r[j] = *(const float2*)(Vb + (size_t)col * kD + d0);
            }
            u32x4 t0, t1;
            t0.x = pk2(r[0].x,r[1].x); t0.y = pk2(r[2].x,r[3].x);
            t0.z = pk2(r[4].x,r[5].x); t0.w = pk2(r[6].x,r[7].x);
            t1.x = pk2(r[0].y,r[1].y); t1.y = pk2(r[2].y,r[3].y);
            t1.z = pk2(r[4].y,r[5].y); t1.w = pk2(r[6].y,r[7].y);
            const unsigned b0 = (unsigned)(d0*128 + c0*2)       ^ (((unsigned)(d0 & 7)) << 4);
            const unsigned b1 = (unsigned)((d0+1)*128 + c0*2)   ^ (((unsigned)((d0+1) & 7)) << 4);
            *(u32x4*)(vsb + b0) = t0;
            *(u32x4*)(vsb + b1) = t1;
        }
    };

    auto compute = [&](int s) {
        const int nn = (s == 9 || (s == 10 && R == 0)) ? 2 : 4;
        if (s == 11 && wg != 0) return;     // pure-special seg: only wg0's row active
        unsigned char* ps = lds + 32768 + wv * 4096;

        f32x4 sf[2][4];
#pragma unroll
        for (int m = 0; m < 2; ++m)
#pragma unroll
        for (int n = 0; n < 4; ++n) sf[m][n] = (f32x4){0.f,0.f,0.f,0.f};

        __builtin_amdgcn_s_setprio(1);
#pragma unroll
        for (int n = 0; n < 4; ++n) if (n < nn) {
            const int c = lm + 16*n;
#pragma unroll
            for (int kk = 0; kk < 2; ++kk) {
                const unsigned byte = (unsigned)(c*128 + kk*64 + g*16) ^ (((unsigned)(c & 7)) << 4);
                const short8 kf = *(const short8*)(ksb + byte);
                sf[0][n] = __builtin_amdgcn_mfma_f32_16x16x32_bf16(qa[0][kk], kf, sf[0][n], 0, 0, 0);
                sf[1][n] = __builtin_amdgcn_mfma_f32_16x16x32_bf16(qa[1][kk], kf, sf[1][n], 0, 0, 0);
            }
        }
        __builtin_amdgcn_s_setprio(0);

        if (s >= 8) {
#pragma unroll
            for (int n = 0; n < 4; ++n) if (n < nn) {
                const int p = lm + 16*n;
#pragma unroll
                for (int m = 0; m < 2; ++m)
#pragma unroll
                for (int i = 0; i < 4; ++i)
                    if (!maskOf(s, p, arow[m][i], A, R)) sf[m][n][i] = -1e30f;
            }
        }

        // online softmax with defer-max (THR=8)
        float tmx[2][4]; bool need = false;
#pragma unroll
        for (int m = 0; m < 2; ++m)
#pragma unroll
        for (int i = 0; i < 4; ++i) {
            float t = sf[m][0][i];
#pragma unroll
            for (int n = 1; n < 4; ++n) if (n < nn) t = fmaxf(t, sf[m][n][i]);
            t = fmaxf(t, __shfl_xor(t, 1));
            t = fmaxf(t, __shfl_xor(t, 2));
            t = fmaxf(t, __shfl_xor(t, 4));
            t = fmaxf(t, __shfl_xor(t, 8));
            tmx[m][i] = t;
            need = need || (t > mrun[m][i] + 8.f);
        }
        if (__any(need)) {
#pragma unroll
            for (int m = 0; m < 2; ++m)
#pragma unroll
            for (int i = 0; i < 4; ++i) {
                const float nm = fmaxf(mrun[m][i], tmx[m][i]);
                const float al = __expf(mrun[m][i] - nm);
                mrun[m][i] = nm; lpar[m][i] *= al;
#pragma unroll
                for (int nv = 0; nv < 4; ++nv) o[m][nv][i] *= al;
            }
        }
#pragma unroll
        for (int m = 0; m < 2; ++m)
#pragma unroll
        for (int i = 0; i < 4; ++i) {
            const int row = g*4 + i + 16*m;
            const unsigned sw = ((unsigned)(row & 7)) << 4;
            float psum = 0.f;
#pragma unroll
            for (int n = 0; n < 4; ++n) if (n < nn) {
                const float p = __expf(sf[m][n][i] - mrun[m][i]);   // masked -> 0
                psum += p;
                const unsigned byte = ((unsigned)(row*128 + (lm + 16*n)*2)) ^ sw;
                *(unsigned short*)(ps + byte) = bf1(p);
            }
            lpar[m][i] += psum;
        }

        short8 pa[2][2];
#pragma unroll
        for (int mp = 0; mp < 2; ++mp)
#pragma unroll
        for (int kpv = 0; kpv < 2; ++kpv) if (2*kpv < nn) {
            const int row = lm + 16*mp;
            const unsigned byte = ((unsigned)(row*128 + kpv*64 + g*16)) ^ (((unsigned)(row & 7)) << 4);
            pa[mp][kpv] = *(const short8*)(ps + byte);
        }
        __builtin_amdgcn_s_setprio(1);
#pragma unroll
        for (int nv = 0; nv < 4; ++nv)
#pragma unroll
        for (int kpv = 0; kpv < 2; ++kpv) if (2*kpv < nn) {
            const int vd = lm + 16*nv;
            const unsigned byte = ((unsigned)(vd*128 + kpv*64 + g*16)) ^ (((unsigned)(vd & 7)) << 4);
            const short8 vb = *(const short8*)(vsb + byte);
            o[0][nv] = __builtin_amdgcn_mfma_f32_16x16x32_bf16(pa[0][kpv], vb, o[0][nv], 0, 0, 0);
            o[1][nv] = __builtin_amdgcn_mfma_f32_16x16x32_bf16(pa[1][kpv], vb, o[1][nv], 0, 0, 0);
        }
        __builtin_amdgcn_s_setprio(0);
    };

    if (group == 0) stage(0);
    __syncthreads();
    for (int k = 0; k < nseg; ++k) {
        if ((k & 1) == group) compute(k);          // my seg, staged last interval
        else if (k + 1 < nseg) stage(k + 1);       // stage my next seg
        __syncthreads();
    }

    // reduce per-lane row-sum partials across the 16-lane group
#pragma unroll
    for (int m = 0; m < 2; ++m)
#pragma unroll
    for (int i = 0; i < 4; ++i) {
        float v = lpar[m][i];
        v += __shfl_xor(v, 1);
        v += __shfl_xor(v, 2);
        v += __shfl_xor(v, 4);
        v += __shfl_xor(v, 8);
        lpar[m][i] = v;
    }

    // merge group partials (flash-decoding combine), group0 stores
    float* mlb = (float*)(lds + 65536);
    if (group == 1) {
        float* orow = (float*)(lds + wg * 8192);
#pragma unroll
        for (int m = 0; m < 2; ++m)
#pragma unroll
        for (int i = 0; i < 4; ++i) {
            const int row = g*4 + i + 16*m;
            if (lm == 0) {
                mlb[(wg*32 + row)*2 + 0] = mrun[m][i];
                mlb[(wg*32 + row)*2 + 1] = lpar[m][i];
            }
#pragma unroll
            for (int nv = 0; nv < 4; ++nv)
                orow[row*64 + lm + 16*nv] = o[m][nv][i];
        }
    }
    __syncthreads();
    if (group == 0) {
        const float* orow = (const float*)(lds + wg * 8192);
#pragma unroll
        for (int m = 0; m < 2; ++m)
#pragma unroll
        for (int i = 0; i < 4; ++i) {
            const int row = g*4 + i + 16*m;
            const float m1 = mlb[(wg*32 + row)*2 + 0];
            const float l1 = mlb[(wg*32 + row)*2 + 1];
            const float m0 = mrun[m][i], l0 = lpar[m][i];
            const float M  = fmaxf(m0, m1);
            const float w0 = __expf(m0 - M), w1 = __expf(m1 - M);
            const float inv = 1.f / (l0*w0 + l1*w1);
            float* op = Out + ((size_t)bh * kS + rowbase + row) * kD + lm;
#pragma unroll
            for (int nv = 0; nv < 4; ++nv)
                op[16*nv] = (o[m][nv][i]*w0 + orow[row*64 + lm + 16*nv]*w1) * inv;
        }
    }
}

} // namespace

extern "C" void kernel_launch(void* const* d_in, const int* in_sizes, int n_in,
                              void* d_out, int out_size, void* d_ws, size_t ws_size,
                              hipStream_t stream) {
    const float* q = (const float*)d_in[0];
    const float* k = (const float*)d_in[1];
    const float* v = (const float*)d_in[2];
    // d_in[3] (mask) is a pure function of (S,STRIDE,EXPR) reproduced in-kernel.
    float* out = (float*)d_out;
    dim3 grid(512), block(512);
    hipLaunchKernelGGL(sparse_attn2, grid, block, 0, stream, q, k, v, out);
}

// Round 5
// 74.769 us; speedup vs baseline: 2.3753x; 2.3753x over previous
//
#include <hip/hip_runtime.h>
#include <math.h>

// SparseMultiheadAttention B=2,H=16,S=2048,DH=64, STRIDE=128, EXPR=32, bidirectional.
// Mask factorization (HW-validated rounds 0-2):
//   allowed(i,c) = (c&127)>=96 | ((c&127)==0 && c>0) | ((c>>7)==a(i))
//   a(i) = (i>>7) - ((i&127)==0 && i>0)
// Round-1 schedule (proven): every thread stages seg s+1 (double-buffered LDS)
// then computes seg s; one barrier per segment. Round-2's stagger REVERTED
// (staging latency went on the critical path; FETCH 3x, dur 2x).
// Block = 64 rows (4 waves x 16 rows), grid = 32 bh x 32 row-blocks = 1024.
// 64-col segments, A = row-block's 128-block = R64>>1:
//   s0..7 : summary pairs [256s+96,+128) u [256s+224,+256)       no mask
//   s8    : local [128A, +64)                                     mask a_row==A
//   s9    : local [128A+64,+96) (32) + checkpoints {128k,k=1..15}+pad (16), nn=3
//           sub-tiles 0,1: mask a_row==A; sub-tile 2: mask (p<47 && a_row!=p-31)
//   s10/11: special block A-1 [128(A-1),+64),[+64,+96) nn=4/2; mask a_row==A-1;
//           only exist when R64 even && >0 (row 128A present); wave 0 computes.
// Coverage: summary once; local block once (col 128A masked in checkpoint tile,
// unmasked in s8; col 128(A-1) masked in checkpoint tile for the special row,
// unmasked in s10); checkpoints k!=a_row once. Verified per-row.

namespace {

constexpr int kS = 2048, kD = 64;

typedef __attribute__((ext_vector_type(8))) short short8;
typedef __attribute__((ext_vector_type(4))) float f32x4;
typedef __attribute__((ext_vector_type(4))) unsigned int u32x4;

__device__ __forceinline__ unsigned f2bf(float f) {           // RNE (Q only)
    unsigned u = __builtin_bit_cast(unsigned, f);
    u += 0x7fffu + ((u >> 16) & 1u);
    return u >> 16;
}
__device__ __forceinline__ unsigned pk2(float a, float b) {   // RNE pair
    return f2bf(a) | (f2bf(b) << 16);
}
__device__ __forceinline__ unsigned pkt(float a, float b) {   // truncating pair: 1 v_perm
    return __builtin_amdgcn_perm(__builtin_bit_cast(unsigned, b),
                                 __builtin_bit_cast(unsigned, a), 0x07060302u);
}

__device__ __forceinline__ int seglen(int s) { return s == 9 ? 48 : (s == 11 ? 32 : 64); }

__device__ __forceinline__ int colOf(int s, int p, int A) {
    if (s < 8)  return 256 * s + (p < 32 ? 96 + p : 192 + p);
    if (s == 8) return 128 * A + p;
    if (s == 9) {
        if (p < 32) return 128 * A + 64 + p;
        const int k = p - 31;                 // 1..16
        return k < 16 ? 128 * k : 2047;       // p=47 pad (always masked)
    }
    if (s == 10) return 128 * (A - 1) + p;
    return 128 * (A - 1) + 64 + p;            // s==11
}
__device__ __forceinline__ bool maskOf(int s, int p, int a_row, int A) {
    if (s < 8)  return true;
    if (s == 8) return a_row == A;
    if (s == 9) return p < 32 ? (a_row == A) : (p < 47 && a_row != (p - 31));
    return a_row == A - 1;                    // s==10/11
}

__global__ __launch_bounds__(256, 4) void sparse_attn3(
    const float* __restrict__ Q, const float* __restrict__ K,
    const float* __restrict__ V, float* __restrict__ Out)
{
    // [0,16K):   K dbuf 2 x 8KB  [c(64)][d(64)] bf16, swz byte ^= (c&7)<<4
    // [16K,32K): V^T dbuf 2 x 8KB [d(64)][c(64)] bf16, swz byte ^= (d&7)<<4
    // [32K,40K): ps 4 waves x 2KB [row(16)][c(64)] bf16, swz byte ^= (row&7)<<4
    __shared__ __align__(16) unsigned char lds[40960];

    const int tid = threadIdx.x;
    const int wv = tid >> 6;
    const int l = tid & 63, g = l >> 4, lm = l & 15;
    const int bh = blockIdx.x >> 5, R64 = blockIdx.x & 31;
    const int A = R64 >> 1;
    const int rowbase = R64 * 64 + wv * 16;
    const bool spec = ((R64 & 1) == 0) && (R64 > 0);
    const int nseg = spec ? 12 : 10;

    const float* Qb = Q + (size_t)bh * kS * kD;
    const float* Kb = K + (size_t)bh * kS * kD;
    const float* Vb = V + (size_t)bh * kS * kD;

    // Q A-fragment (row = lm, k = g*8+j+32kk), pre-scaled by 1/8, RNE
    short8 qa[2];
#pragma unroll
    for (int kk = 0; kk < 2; ++kk) {
        const float* qp = Qb + (size_t)(rowbase + lm) * kD + kk*32 + g*8;
        float4 a = *(const float4*)qp;
        float4 b = *(const float4*)(qp + 4);
        u32x4 t;
        t.x = pk2(a.x*0.125f, a.y*0.125f);
        t.y = pk2(a.z*0.125f, a.w*0.125f);
        t.z = pk2(b.x*0.125f, b.y*0.125f);
        t.w = pk2(b.z*0.125f, b.w*0.125f);
        qa[kk] = __builtin_bit_cast(short8, t);
    }

    int arow[4];
#pragma unroll
    for (int i = 0; i < 4; ++i) {
        const int ig = rowbase + g*4 + i;
        arow[i] = (ig >> 7) - (((ig & 127) == 0 && ig > 0) ? 1 : 0);
    }

    float mrun[4], lpar[4];
    f32x4 o[4];
#pragma unroll
    for (int i = 0; i < 4; ++i) { mrun[i] = -1e30f; lpar[i] = 0.f; }
#pragma unroll
    for (int nv = 0; nv < 4; ++nv) o[nv] = (f32x4){0.f,0.f,0.f,0.f};

    auto stage = [&](int s, int buf) {
        unsigned char* ksb = lds + buf * 8192;
        unsigned char* vsb = lds + 16384 + buf * 8192;
        const int len = seglen(s);
        {   // K: thread (c = tid>>2, q4 = tid&3) loads 16 consecutive d-floats
            const int c = tid >> 2, q4 = tid & 3;
            if (c < len) {
                const int col = colOf(s, c, A);
                const float* kp = Kb + (size_t)col * kD + q4*16;
                float4 k0 = *(const float4*)(kp);
                float4 k1 = *(const float4*)(kp + 4);
                float4 k2 = *(const float4*)(kp + 8);
                float4 k3 = *(const float4*)(kp + 12);
                u32x4 lo, hi;
                lo.x = pkt(k0.x,k0.y); lo.y = pkt(k0.z,k0.w);
                lo.z = pkt(k1.x,k1.y); lo.w = pkt(k1.z,k1.w);
                hi.x = pkt(k2.x,k2.y); hi.y = pkt(k2.z,k2.w);
                hi.z = pkt(k3.x,k3.y); hi.w = pkt(k3.z,k3.w);
                const unsigned b  = (unsigned)(c*128 + q4*32);
                const unsigned sw = ((unsigned)(c & 7)) << 4;
                *(u32x4*)(ksb + (b ^ sw))        = lo;
                *(u32x4*)(ksb + ((b ^ sw) ^ 16)) = hi;
            }
        }
        {   // V^T: thread (c0 = (tid>>5)*8, d0 = (tid&31)*2) gathers 8 cols
            const int c0 = (tid >> 5) * 8, d0 = (tid & 31) * 2;
            if (c0 < len) {
                float2 r[8];
#pragma unroll
                for (int j = 0; j < 8; ++j) {
                    const int col = colOf(s, c0 + j, A);
                    r[j] = *(const float2*)(Vb + (size_t)col * kD + d0);
                }
                u32x4 t0, t1;
                t0.x = pkt(r[0].x,r[1].x); t0.y = pkt(r[2].x,r[3].x);
                t0.z = pkt(r[4].x,r[5].x); t0.w = pkt(r[6].x,r[7].x);
                t1.x = pkt(r[0].y,r[1].y); t1.y = pkt(r[2].y,r[3].y);
                t1.z = pkt(r[4].y,r[5].y); t1.w = pkt(r[6].y,r[7].y);
                const unsigned b0 = (unsigned)(d0*128 + c0*2)     ^ (((unsigned)(d0 & 7)) << 4);
                const unsigned b1 = (unsigned)((d0+1)*128 + c0*2) ^ (((unsigned)((d0+1) & 7)) << 4);
                *(u32x4*)(vsb + b0) = t0;
                *(u32x4*)(vsb + b1) = t1;
            }
        }
    };

    auto compute = [&](int s, int buf) {
        if (s >= 10 && wv != 0) return;      // special block: only wave 0's rows
        const int nn = (s == 9) ? 3 : ((s == 11) ? 2 : 4);
        const unsigned char* ksb = lds + buf * 8192;
        const unsigned char* vsb = lds + 16384 + buf * 8192;
        unsigned char* ps = lds + 32768 + wv * 2048;

        f32x4 sf[4];
#pragma unroll
        for (int n = 0; n < 4; ++n) sf[n] = (f32x4){0.f,0.f,0.f,0.f};

        __builtin_amdgcn_s_setprio(1);
#pragma unroll
        for (int n = 0; n < 4; ++n) if (n < nn) {
            const int c = lm + 16*n;
#pragma unroll
            for (int kk = 0; kk < 2; ++kk) {
                const unsigned byte = (unsigned)(c*128 + kk*64 + g*16) ^ (((unsigned)(c & 7)) << 4);
                const short8 kf = *(const short8*)(ksb + byte);
                sf[n] = __builtin_amdgcn_mfma_f32_16x16x32_bf16(qa[kk], kf, sf[n], 0, 0, 0);
            }
        }
        __builtin_amdgcn_s_setprio(0);

        if (s >= 8) {
#pragma unroll
            for (int n = 0; n < 4; ++n) if (n < nn) {
                const int p = lm + 16*n;
#pragma unroll
                for (int i = 0; i < 4; ++i)
                    if (!maskOf(s, p, arow[i], A)) sf[n][i] = -1e30f;
            }
        }

        // online softmax with defer-max (THR=8)
        float tmx[4]; bool need = false;
#pragma unroll
        for (int i = 0; i < 4; ++i) {
            float t = sf[0][i];
#pragma unroll
            for (int n = 1; n < 4; ++n) if (n < nn) t = fmaxf(t, sf[n][i]);
            t = fmaxf(t, __shfl_xor(t, 1));
            t = fmaxf(t, __shfl_xor(t, 2));
            t = fmaxf(t, __shfl_xor(t, 4));
            t = fmaxf(t, __shfl_xor(t, 8));
            tmx[i] = t;
            need = need || (t > mrun[i] + 8.f);
        }
        if (__any(need)) {
#pragma unroll
            for (int i = 0; i < 4; ++i) {
                const float nm = fmaxf(mrun[i], tmx[i]);
                const float al = __expf(mrun[i] - nm);
                mrun[i] = nm; lpar[i] *= al;
#pragma unroll
                for (int nv = 0; nv < 4; ++nv) o[nv][i] *= al;
            }
        }
        const int nwr = (nn + 1) & ~1;       // 4,4,2: zero-fill n=3 when nn==3
#pragma unroll
        for (int i = 0; i < 4; ++i) {
            const int row = g*4 + i;
            const unsigned sw = ((unsigned)(row & 7)) << 4;
            float psum = 0.f;
#pragma unroll
            for (int n = 0; n < 4; ++n) if (n < nwr) {
                const float p = (n < nn) ? __expf(sf[n][i] - mrun[i]) : 0.f;
                psum += p;
                const unsigned byte = ((unsigned)(row*128 + (lm + 16*n)*2)) ^ sw;
                *(unsigned short*)(ps + byte) = (unsigned short)(pkt(p, 0.f) & 0xffffu);
            }
            lpar[i] += psum;
        }

        short8 pa[2];
#pragma unroll
        for (int kpv = 0; kpv < 2; ++kpv) if (2*kpv < nn) {
            const unsigned byte = ((unsigned)(lm*128 + kpv*64 + g*16)) ^ (((unsigned)(lm & 7)) << 4);
            pa[kpv] = *(const short8*)(ps + byte);
        }
        __builtin_amdgcn_s_setprio(1);
#pragma unroll
        for (int nv = 0; nv < 4; ++nv)
#pragma unroll
        for (int kpv = 0; kpv < 2; ++kpv) if (2*kpv < nn) {
            const int vd = lm + 16*nv;
            const unsigned byte = ((unsigned)(vd*128 + kpv*64 + g*16)) ^ (((unsigned)(vd & 7)) << 4);
            const short8 vb = *(const short8*)(vsb + byte);
            o[nv] = __builtin_amdgcn_mfma_f32_16x16x32_bf16(pa[kpv], vb, o[nv], 0, 0, 0);
        }
        __builtin_amdgcn_s_setprio(0);
    };

    stage(0, 0);
    __syncthreads();
    for (int s = 0; s < nseg; ++s) {
        if (s + 1 < nseg) stage(s + 1, (s + 1) & 1);   // issue-ahead, dbl-buffered
        compute(s, s & 1);
        __syncthreads();
    }

    // epilogue: reduce row sums across the 16-lane group, normalize, store fp32
#pragma unroll
    for (int i = 0; i < 4; ++i) {
        float v = lpar[i];
        v += __shfl_xor(v, 1);
        v += __shfl_xor(v, 2);
        v += __shfl_xor(v, 4);
        v += __shfl_xor(v, 8);
        const float inv = 1.f / v;
        float* op = Out + ((size_t)bh * kS + rowbase + g*4 + i) * kD + lm;
#pragma unroll
        for (int nv = 0; nv < 4; ++nv)
            op[16*nv] = o[nv][i] * inv;
    }
}

} // namespace

extern "C" void kernel_launch(void* const* d_in, const int* in_sizes, int n_in,
                              void* d_out, int out_size, void* d_ws, size_t ws_size,
                              hipStream_t stream) {
    const float* q = (const float*)d_in[0];
    const float* k = (const float*)d_in[1];
    const float* v = (const float*)d_in[2];
    // d_in[3] (mask) is a pure function of (S,STRIDE,EXPR) reproduced in-kernel.
    float* out = (float*)d_out;
    dim3 grid(1024), block(256);
    hipLaunchKernelGGL(sparse_attn3, grid, block, 0, stream, q, k, v, out);
}